// Round 26
// baseline (6147.729 us; speedup 1.0000x reference)
//
#include <hip/hip_runtime.h>

// Numerics frozen from R20 (PASSED, absmax 0.0039):
//  conv1: (kh,kw,ic) flat FMA chain; conv2: (kh,kw,ic) with 4 panel chains
//  split at k=152/304/456, joined ((P0+P1)+P2)+P3 then bias; LIF f32
//  two-rounding v+0.5*(x-v); head: ascending-oc sequential chain per c.
// R26 = R25 with the conv2 selector work SPLIT across pipes:
//  SEG_C (first half of each range): uniform b01 in {1.0,0.0} + v_fmac
//    (SALU cond-select + 1 VALU) — fma(1,w,acc)=round(acc+w); fma(0,w,acc)=acc.
//  SEG_V (second half): mask copied to VGPR via mbcnt_lo(0,M) (opaque to the
//    scalarizer) then v_bfe+v_and+v_add (3 VALU, 0 SALU).
//  ~50/50 mix => SALU ~= VALU ~= 1.47M cy/CU (both pipes saturated).

#define NB    8
#define HW    128
#define NPIX  (HW*HW)          // 16384
#define NT    5

// ---------------- W2 [oc][ic][tap] -> Wt [tap][ic][oc]
__global__ void k_transpose_w2(const float* __restrict__ W2, float* __restrict__ Wt) {
    int i = blockIdx.x * 256 + threadIdx.x;      // 36864
    if (i >= 9 * 64 * 64) return;
    int oc = i & 63;
    int ic = (i >> 6) & 63;
    int tap = i >> 12;
    Wt[i] = W2[(oc * 64 + ic) * 9 + tap];
}

// ---------------- conv1 ((kh,kw,ic) flat FMA) + LIF1 -> ballot-packed masks
__global__ __launch_bounds__(256) void k_conv1_lif1(
    const float* __restrict__ lab, const float* __restrict__ W1,
    const float* __restrict__ b1, const float* __restrict__ tau1,
    unsigned long long* __restrict__ smask)
{
#pragma clang fp contract(off)
    __shared__ float w1s[64 * 27];
    __shared__ float b1s[64];
    {
        int tid = threadIdx.x;
        for (int e = tid; e < 64 * 27; e += 256) w1s[e] = W1[e];
        if (tid < 64) b1s[tid] = b1[tid];
        __syncthreads();
    }
    int g = blockIdx.x * 256 + threadIdx.x;      // (b,y,x,oc) — lane = oc
    int oc = g & 63;
    int x = (g >> 6) & (HW - 1);
    int y = (g >> 13) & (HW - 1);
    int b = g >> 20;

    const float* wbase = w1s + oc * 27;
    const float* ibase = lab + b * 3 * NPIX;
    float acc = 0.f;
    for (int kh = 0; kh < 3; ++kh) {             // identical chain to R20
        int yy = y + kh - 1;
        if ((unsigned)yy >= (unsigned)HW) continue;
        for (int kw = 0; kw < 3; ++kw) {
            int xx = x + kw - 1;
            if ((unsigned)xx >= (unsigned)HW) continue;
            const float* px = ibase + yy * HW + xx;
#pragma unroll
            for (int ic = 0; ic < 3; ++ic) {
                acc = __builtin_fmaf(wbase[ic * 9 + kh * 3 + kw], px[ic * NPIX], acc);
            }
        }
    }
    float xin = acc + b1s[oc];

    float tauc = fminf(fmaxf(tau1[0], 0.5f), 5.0f);
    float it = 1.0f / tauc;

    float v = 0.f;
    unsigned bits = 0;
    for (int t = 0; t < NT; ++t) {
        float d = xin - v;
        float m = it * d;
        v = v + m;
        bool s = (v - 0.1f) >= 0.f;
        float vr = s ? 0.f : v;
        vr = fmaxf(vr, -2.f);
        vr = fminf(vr, 2.f);
        v = vr;
        if (s) bits |= (1u << t);
    }
    for (int t = 0; t < NT; ++t) {
        unsigned long long bal = __ballot((bits >> t) & 1);
        if (oc == 0) smask[((size_t)(b * NT + t) * NPIX) + y * HW + x] = bal;
    }
}

// ---------------- conv2 (packed, all t) + LIF2 -> s2 masks
// wave = strip of 8 pixels, lane = oc. Mixed scalar/vector selector paths.
#define SEG_C(IC0, IC1, M, SH, PN)                                      \
    for (int ic = IC0; ic < IC1; ++ic) {                                \
        float wf = __uint_as_float(wtu[ic * 64]);                       \
        _Pragma("unroll")                                               \
        for (int p = 0; p < 8; ++p) {                                   \
            float b01 = ((M[p] >> (ic - SH)) & 1u) ? 1.0f : 0.0f;       \
            acc[p][PN] = __builtin_fmaf(b01, wf, acc[p][PN]);           \
        }                                                               \
    }

#define SEG_V(IC0, IC1, VM, SH, PN)                                     \
    for (int ic = IC0; ic < IC1; ++ic) {                                \
        unsigned wb = wtu[ic * 64];                                     \
        _Pragma("unroll")                                               \
        for (int p = 0; p < 8; ++p) {                                   \
            unsigned nb = (unsigned)(((int)(VM[p] << (31 - (ic - SH)))) >> 31); \
            acc[p][PN] = acc[p][PN] + __uint_as_float(wb & nb);         \
        }                                                               \
    }

#define TAP(KH, KW, SEGS) {                                             \
    const int yy = y + KH - 1;                                          \
    const bool vy = (unsigned)yy < (unsigned)HW;                        \
    unsigned Mlo[8], Mhi[8], Vlo[8], Vhi[8];                            \
    _Pragma("unroll")                                                   \
    for (int p = 0; p < 8; ++p) {                                       \
        int xx = x0 + KW - 1 + p;                                       \
        unsigned long long mm = (vy && (unsigned)xx < (unsigned)HW)     \
                                ? smb[yy * HW + xx] : 0ULL;             \
        Mlo[p] = (unsigned)mm; Mhi[p] = (unsigned)(mm >> 32);           \
        Vlo[p] = __builtin_amdgcn_mbcnt_lo(0u, Mlo[p]);                 \
        Vhi[p] = __builtin_amdgcn_mbcnt_lo(0u, Mhi[p]);                 \
    }                                                                   \
    const unsigned* wtu = (const unsigned*)(Wt + (KH * 3 + KW) * 4096) + oc; \
    SEGS }

__global__ __launch_bounds__(256) void k_conv2_lif2(
    const unsigned long long* __restrict__ smask,
    const float* __restrict__ Wt, const float* __restrict__ b2,
    const float* __restrict__ tau2, unsigned long long* __restrict__ s2m)
{
#pragma clang fp contract(off)
    const int tid = threadIdx.x;
    const int oc = tid & 63;
    const int wid = __builtin_amdgcn_readfirstlane(blockIdx.x * 4 + (tid >> 6));
    const int b = wid >> 11;
    const int rem = wid & 2047;
    const int y = rem >> 4;
    const int x0 = (rem & 15) * 8;

    const float b2oc = b2[oc];
    float tauc = fminf(fmaxf(tau2[0], 0.5f), 5.0f);
    const float it = 1.0f / tauc;

    float v[8];
    for (int t = 0; t < NT; ++t) {
        float acc[8][4];
#pragma unroll
        for (int p = 0; p < 8; ++p) {
            acc[p][0] = 0.f; acc[p][1] = 0.f; acc[p][2] = 0.f; acc[p][3] = 0.f;
        }
        const unsigned long long* smb = smask + (size_t)(b * NT + t) * NPIX;

        // taps (kh,kw) ascending; ic ascending; panels split at k=152/304/456.
        // Each range: first half scalar-path (C), second half vector-path (V).
        TAP(0, 0, SEG_C(0,16,Mlo,0,0)  SEG_V(16,32,Vlo,0,0)
                  SEG_C(32,48,Mhi,32,0) SEG_V(48,64,Vhi,32,0))
        TAP(0, 1, SEG_C(0,16,Mlo,0,0)  SEG_V(16,32,Vlo,0,0)
                  SEG_C(32,48,Mhi,32,0) SEG_V(48,64,Vhi,32,0))
        TAP(0, 2, SEG_C(0,12,Mlo,0,0)  SEG_V(12,24,Vlo,0,0)
                  SEG_C(24,28,Mlo,0,1) SEG_V(28,32,Vlo,0,1)
                  SEG_C(32,48,Mhi,32,1) SEG_V(48,64,Vhi,32,1))
        TAP(1, 0, SEG_C(0,16,Mlo,0,1)  SEG_V(16,32,Vlo,0,1)
                  SEG_C(32,48,Mhi,32,1) SEG_V(48,64,Vhi,32,1))
        TAP(1, 1, SEG_C(0,16,Mlo,0,1)  SEG_V(16,32,Vlo,0,1)
                  SEG_C(32,40,Mhi,32,1) SEG_V(40,48,Vhi,32,1)
                  SEG_C(48,56,Mhi,32,2) SEG_V(56,64,Vhi,32,2))
        TAP(1, 2, SEG_C(0,16,Mlo,0,2)  SEG_V(16,32,Vlo,0,2)
                  SEG_C(32,48,Mhi,32,2) SEG_V(48,64,Vhi,32,2))
        TAP(2, 0, SEG_C(0,16,Mlo,0,2)  SEG_V(16,32,Vlo,0,2)
                  SEG_C(32,48,Mhi,32,2) SEG_V(48,64,Vhi,32,2))
        TAP(2, 1, SEG_C(0,4,Mlo,0,2)   SEG_V(4,8,Vlo,0,2)
                  SEG_C(8,20,Mlo,0,3)  SEG_V(20,32,Vlo,0,3)
                  SEG_C(32,48,Mhi,32,3) SEG_V(48,64,Vhi,32,3))
        TAP(2, 2, SEG_C(0,16,Mlo,0,3)  SEG_V(16,32,Vlo,0,3)
                  SEG_C(32,48,Mhi,32,3) SEG_V(48,64,Vhi,32,3))

        unsigned long long* s2mb = s2m + (size_t)(b * NT + t) * NPIX;
#pragma unroll
        for (int p = 0; p < 8; ++p) {
            float x2 = (((acc[p][0] + acc[p][1]) + acc[p][2]) + acc[p][3]) + b2oc;
            float vp = (t == 0) ? 0.f : v[p];
            float d = x2 - vp;
            float m = it * d;
            vp = vp + m;
            bool s = (vp - 0.1f) >= 0.f;
            float vr = s ? 0.f : vp;
            vr = fmaxf(vr, -2.f);
            vr = fminf(vr, 2.f);
            v[p] = vr;
            unsigned long long bal = __ballot(s);
            if (oc == 0) s2mb[y * HW + x0 + p] = bal;
        }
    }
}

// ---------------- head 1x1 from packed s2 masks
__global__ __launch_bounds__(256) void k_head(
    const unsigned long long* __restrict__ s2m, const float* __restrict__ Wh,
    const float* __restrict__ bh, float* __restrict__ out)
{
#pragma clang fp contract(off)
    __shared__ float whs[192];
    __shared__ float bhs[3];
    {
        int tid = threadIdx.x;
        if (tid < 192) whs[tid] = Wh[tid];
        if (tid < 3) bhs[tid] = bh[tid];
        __syncthreads();
    }
    int g = blockIdx.x * 256 + threadIdx.x;      // (t,b,px): 5*8*16384
    int px = g & (NPIX - 1);
    int r = g >> 14;
    int b = r & 7;
    int t = r >> 3;

    unsigned long long m = s2m[(size_t)(b * NT + t) * NPIX + px];
    unsigned mlo = (unsigned)m, mhi = (unsigned)(m >> 32);
    float c0 = 0.f, c1 = 0.f, c2 = 0.f;
    for (int oc = 0; oc < 32; ++oc) {            // ascending oc — frozen chain
        unsigned bit = (mlo >> oc) & 1u;
        if (bit) { c0 = c0 + whs[oc]; c1 = c1 + whs[64 + oc]; c2 = c2 + whs[128 + oc]; }
    }
    for (int oc = 32; oc < 64; ++oc) {
        unsigned bit = (mhi >> (oc - 32)) & 1u;
        if (bit) { c0 = c0 + whs[oc]; c1 = c1 + whs[64 + oc]; c2 = c2 + whs[128 + oc]; }
    }
    int obase = ((t * NB + b) * 3) * NPIX + px;
    out[obase] = c0 + bhs[0];
    out[obase + NPIX] = c1 + bhs[1];
    out[obase + 2 * NPIX] = c2 + bhs[2];
}

extern "C" void kernel_launch(void* const* d_in, const int* in_sizes, int n_in,
                              void* d_out, int out_size, void* d_ws, size_t ws_size,
                              hipStream_t stream) {
    const float* lab  = (const float*)d_in[0];
    const float* W1   = (const float*)d_in[1];
    const float* b1   = (const float*)d_in[2];
    const float* tau1 = (const float*)d_in[3];
    const float* W2   = (const float*)d_in[4];
    const float* b2   = (const float*)d_in[5];
    const float* tau2 = (const float*)d_in[6];
    const float* Wh   = (const float*)d_in[7];
    const float* bh   = (const float*)d_in[8];
    float* out = (float*)d_out;

    // ws: smask 5.25MB | s2mask 5.25MB | Wt 147KB
    const size_t SZ_SM = (size_t)NB * NT * NPIX * 8;         // 5,242,880
    const size_t SZ_WT = 9 * 64 * 64 * 4;                    //   147,456
    if (ws_size < 2 * SZ_SM + SZ_WT) return;

    char* ws = (char*)d_ws;
    unsigned long long* smask = (unsigned long long*)ws;
    unsigned long long* s2m   = (unsigned long long*)(ws + SZ_SM);
    float* Wt                 = (float*)(ws + 2 * SZ_SM);

    hipLaunchKernelGGL(k_transpose_w2, dim3(144), dim3(256), 0, stream, W2, Wt);
    hipLaunchKernelGGL(k_conv1_lif1, dim3(NB * 64 * NPIX / 256), dim3(256), 0, stream,
                       lab, W1, b1, tau1, smask);
    hipLaunchKernelGGL(k_conv2_lif2, dim3(4096), dim3(256), 0, stream,
                       smask, Wt, b2, tau2, s2m);
    hipLaunchKernelGGL(k_head, dim3(NT * NB * NPIX / 256), dim3(256), 0, stream,
                       s2m, Wh, bh, out);
}

// Round 27
// 3842.002 us; speedup vs baseline: 1.6001x; 1.6001x over previous
//
#include <hip/hip_runtime.h>

// Numerics frozen from R20 (PASSED, absmax 0.0039):
//  conv1: (kh,kw,ic) flat FMA chain (OOB taps exact +0); conv2: (kh,kw,ic)
//  4 panel chains split at k=152/304/456 (tap2:ic24, tap4:ic48, tap7:ic8),
//  joined ((P0+P1)+P2)+P3 then bias; LIF f32 two-rounding v+0.5*(x-v);
//  head: ascending-oc conditional-add chain per c.
// R27: bitplane conv2, t-serial, oc-serial. Per term:
//   v_add_f32 tmp, s_w, acc  +  v_cndmask_b32 acc, acc, tmp, s[mask]
//   = 2 VALU, 0 SALU. Mask u64 (bit=pixel) IS the cndmask selector.
//   bit=0 -> acc unchanged bit-identically (old value selected).
// conv1 / k_shift / head reused from R24 (correctness-verified there).

#define NB    8
#define HW    128
#define NPIX  (HW*HW)          // 16384
#define NT    5

typedef unsigned long long u64;

// ---------------- zero page (64 u64) for OOB rows
__global__ void k_zero(u64* __restrict__ zp) {
    zp[threadIdx.x] = 0ULL;
}

// ---------------- W2 [oc][ic][tap] -> Wt2 [oc][tap][ic]
__global__ void k_transpose_w2(const float* __restrict__ W2, float* __restrict__ Wt2) {
    int i = blockIdx.x * 256 + threadIdx.x;      // 36864
    if (i >= 64 * 9 * 64) return;
    int ic = i & 63;
    int tap = (i >> 6) % 9;
    int oc = i / (9 * 64);
    Wt2[i] = W2[(oc * 64 + ic) * 9 + tap];
}

// ---------------- conv1 + LIF1 -> raw pixel bitplanes rawp[b][t][y][xw][ic]
// wave = 64 pixels of one half-row; oc (= conv2 ic) serial 0..63. (R24, verified)
__global__ __launch_bounds__(256) void k_conv1_lif1(
    const float* __restrict__ lab, const float* __restrict__ W1,
    const float* __restrict__ b1, const float* __restrict__ tau1,
    u64* __restrict__ rawp)
{
#pragma clang fp contract(off)
    __shared__ float w1s[64 * 27];
    __shared__ float b1s[64];
    {
        int tid = threadIdx.x;
        for (int e = tid; e < 64 * 27; e += 256) w1s[e] = W1[e];
        if (tid < 64) b1s[tid] = b1[tid];
        __syncthreads();
    }
    const int tid = threadIdx.x;
    const int lane = tid & 63;
    const int wid = blockIdx.x * 4 + (tid >> 6); // 2048: (b,y,xw)
    const int b = wid >> 8;
    const int rem = wid & 255;
    const int y = rem >> 1;
    const int xw = rem & 1;
    const int x = xw * 64 + lane;

    float nb[3][3][3];                            // [ic][dy][dx], zero-padded
#pragma unroll
    for (int ic = 0; ic < 3; ++ic)
#pragma unroll
        for (int dy = 0; dy < 3; ++dy)
#pragma unroll
            for (int dx = 0; dx < 3; ++dx) {
                int yy = y + dy - 1, xx = x + dx - 1;
                float v = 0.f;
                if ((unsigned)yy < (unsigned)HW && (unsigned)xx < (unsigned)HW)
                    v = lab[(b * 3 + ic) * NPIX + yy * HW + xx];
                nb[ic][dy][dx] = v;
            }

    float tauc = fminf(fmaxf(tau1[0], 0.5f), 5.0f);
    const float it = 1.0f / tauc;

    u64 plane[NT];
#pragma unroll
    for (int t = 0; t < NT; ++t) plane[t] = 0ULL;

    for (int oc = 0; oc < 64; ++oc) {
        const float* w = w1s + oc * 27;
        float acc = 0.f;
#pragma unroll
        for (int kh = 0; kh < 3; ++kh)
#pragma unroll
            for (int kw = 0; kw < 3; ++kw)
#pragma unroll
                for (int ic = 0; ic < 3; ++ic)   // frozen (kh,kw,ic) FMA chain
                    acc = __builtin_fmaf(w[ic * 9 + kh * 3 + kw], nb[ic][kh][kw], acc);
        float xin = acc + b1s[oc];

        float v = 0.f;
#pragma unroll
        for (int t = 0; t < NT; ++t) {
            float d = xin - v;                   // frozen two-rounding LIF
            float m = it * d;
            v = v + m;
            bool s = (v - 0.1f) >= 0.f;
            float vr = s ? 0.f : v;
            vr = fmaxf(vr, -2.f);
            vr = fminf(vr, 2.f);
            v = vr;
            u64 bal = __ballot(s);               // bit i = pixel x0+i
            if (lane == oc) plane[t] = bal;
        }
    }
#pragma unroll
    for (int t = 0; t < NT; ++t)
        rawp[(((size_t)(b * NT + t) * HW + y) * 2 + xw) * 64 + lane] = plane[t];
}

// ---------------- shift: raw planes -> 3 kw-shifted variants (R24, verified)
__global__ __launch_bounds__(256) void k_shift(
    const u64* __restrict__ rawp, u64* __restrict__ sbit)
{
    int g = blockIdx.x * 256 + threadIdx.x;      // 655360
    if (g >= NB * NT * HW * 2 * 64) return;
    int ic = g & 63;
    int xw = (g >> 6) & 1;
    u64 W = rawp[g];
    u64 Wl = xw ? rawp[g - 64] : 0ULL;
    u64 Wr = (xw == 0) ? rawp[g + 64] : 0ULL;
    u64 v0 = (W << 1) | (Wl >> 63);              // kw=0: pixel x-1
    u64 v2 = (W >> 1) | (Wr << 63);              // kw=2: pixel x+1
    size_t base = (size_t)(g >> 6) * 192 + ic;
    sbit[base] = v0;
    sbit[base + 64] = W;
    sbit[base + 128] = v2;
}

// ---------------- conv2 (bitplane cndmask) + LIF2 -> byte spikes [b][t][oc][px]
#define CHAIN(TAPP, IC0, IC1, ACC)                                      \
    _Pragma("unroll 8")                                                 \
    for (int ic = IC0; ic < IC1; ++ic) {                                \
        float w = wrow[(TAPP) * 64 + ic];                               \
        u64 mk = mrow##TAPP[ic];                                        \
        float tmp = ACC + w;                                            \
        asm("v_cndmask_b32 %0, %0, %1, %2" : "+v"(ACC) : "v"(tmp), "s"(mk)); \
    }

__global__ __launch_bounds__(256) void k_conv2_lif2(
    const u64* __restrict__ sbit, const float* __restrict__ Wt2,
    const float* __restrict__ b2, const float* __restrict__ tau2,
    const u64* __restrict__ zpage, unsigned char* __restrict__ s2b)
{
#pragma clang fp contract(off)
    const int tid = threadIdx.x;
    const int lane = tid & 63;
    const int wv = __builtin_amdgcn_readfirstlane(tid >> 6);
    const int pos = blockIdx.x;                  // (b,y,xw): 2048
    const int b = pos >> 8;
    const int rem = pos & 255;
    const int y = rem >> 1;
    const int xw = rem & 1;
    const int x = xw * 64 + lane;

    float tauc = fminf(fmaxf(tau2[0], 0.5f), 5.0f);
    const float it = 1.0f / tauc;

    for (int ocl = 0; ocl < 16; ++ocl) {
        const int oc = wv * 16 + ocl;
        const float* wrow = Wt2 + oc * 576;      // [tap][ic]
        const float b2oc = b2[oc];
        float v = 0.f;
        for (int t = 0; t < NT; ++t) {
            // row base pointers (uniform); OOB row -> zero page (exact skip)
            const size_t tb = (size_t)(b * NT + t) * HW;
            const u64* r0 = (y >= 1)      ? sbit + ((tb + y - 1) * 2 + xw) * 192 : zpage;
            const u64* r1 =                 sbit + ((tb + y    ) * 2 + xw) * 192;
            const u64* r2 = (y <= HW - 2) ? sbit + ((tb + y + 1) * 2 + xw) * 192 : zpage;
            // per-tap mask rows: variant kw at offset kw*64 (zpage: all same zeros)
            const u64* mrow0 = r0;               // (kh0,kw0)
            const u64* mrow1 = (y >= 1) ? r0 + 64 : zpage;
            const u64* mrow2 = (y >= 1) ? r0 + 128 : zpage;
            const u64* mrow3 = r1;               // (kh1,kw0)
            const u64* mrow4 = r1 + 64;
            const u64* mrow5 = r1 + 128;
            const u64* mrow6 = r2;               // (kh2,kw0)
            const u64* mrow7 = (y <= HW - 2) ? r2 + 64 : zpage;
            const u64* mrow8 = (y <= HW - 2) ? r2 + 128 : zpage;

            float a0 = 0.f, a1 = 0.f, a2 = 0.f, a3 = 0.f;
            // frozen chain: taps (kh,kw) ascending, ic ascending,
            // panels split at k=152/304/456
            CHAIN(0, 0, 64, a0)
            CHAIN(1, 0, 64, a0)
            CHAIN(2, 0, 24, a0) CHAIN(2, 24, 64, a1)
            CHAIN(3, 0, 64, a1)
            CHAIN(4, 0, 48, a1) CHAIN(4, 48, 64, a2)
            CHAIN(5, 0, 64, a2)
            CHAIN(6, 0, 64, a2)
            CHAIN(7, 0, 8, a2)  CHAIN(7, 8, 64, a3)
            CHAIN(8, 0, 64, a3)

            float x2 = (((a0 + a1) + a2) + a3) + b2oc;
            float d = x2 - v;                    // frozen LIF chain (t=0: v==0)
            float m = it * d;
            float vp = v + m;
            bool s = (vp - 0.1f) >= 0.f;
            float vr = s ? 0.f : vp;
            vr = fmaxf(vr, -2.f);
            vr = fminf(vr, 2.f);
            v = vr;
            s2b[((size_t)(b * NT + t) * 64 + oc) * NPIX + y * HW + x] = (unsigned char)s;
        }
    }
}

// ---------------- head 1x1 from byte spikes (R23/R24, verified)
__global__ __launch_bounds__(256) void k_head(
    const unsigned char* __restrict__ s2b, const float* __restrict__ Wh,
    const float* __restrict__ bh, float* __restrict__ out)
{
#pragma clang fp contract(off)
    __shared__ float whs[192];
    __shared__ float bhs[3];
    {
        int tid = threadIdx.x;
        if (tid < 192) whs[tid] = Wh[tid];
        if (tid < 3) bhs[tid] = bh[tid];
        __syncthreads();
    }
    int g = blockIdx.x * 256 + threadIdx.x;      // (t,b,px)
    int px = g & (NPIX - 1);
    int r = g >> 14;
    int b = r & 7;
    int t = r >> 3;

    const unsigned char* sp = s2b + ((size_t)(b * NT + t) * 64) * NPIX + px;
    float c0 = 0.f, c1 = 0.f, c2 = 0.f;
    for (int oc = 0; oc < 64; ++oc) {            // ascending oc — frozen chain
        if (sp[oc * NPIX]) {
            c0 = c0 + whs[oc];
            c1 = c1 + whs[64 + oc];
            c2 = c2 + whs[128 + oc];
        }
    }
    int obase = ((t * NB + b) * 3) * NPIX + px;
    out[obase] = c0 + bhs[0];
    out[obase + NPIX] = c1 + bhs[1];
    out[obase + 2 * NPIX] = c2 + bhs[2];
}

extern "C" void kernel_launch(void* const* d_in, const int* in_sizes, int n_in,
                              void* d_out, int out_size, void* d_ws, size_t ws_size,
                              hipStream_t stream) {
    const float* lab  = (const float*)d_in[0];
    const float* W1   = (const float*)d_in[1];
    const float* b1   = (const float*)d_in[2];
    const float* tau1 = (const float*)d_in[3];
    const float* W2   = (const float*)d_in[4];
    const float* b2   = (const float*)d_in[5];
    const float* tau2 = (const float*)d_in[6];
    const float* Wh   = (const float*)d_in[7];
    const float* bh   = (const float*)d_in[8];
    float* out = (float*)d_out;

    const size_t SZ_RAW = (size_t)NB * NT * HW * 2 * 64 * 8;     //  5,242,880
    const size_t SZ_SB  = 3 * SZ_RAW;                            // 15,728,640
    const size_t SZ_S2  = (size_t)NB * NT * 64 * NPIX;           // 41,943,040
    const size_t SZ_WT  = 64 * 9 * 64 * 4;                       //    147,456
    const size_t SZ_ZP  = 64 * 8;                                //        512
    if (ws_size < SZ_RAW + SZ_SB + SZ_S2 + SZ_WT + SZ_ZP) return;

    char* ws = (char*)d_ws;
    u64* rawp          = (u64*)ws;
    u64* sbit          = (u64*)(ws + SZ_RAW);
    unsigned char* s2b = (unsigned char*)(ws + SZ_RAW + SZ_SB);
    float* Wt2         = (float*)(ws + SZ_RAW + SZ_SB + SZ_S2);
    u64* zpage         = (u64*)(ws + SZ_RAW + SZ_SB + SZ_S2 + SZ_WT);

    hipLaunchKernelGGL(k_zero, dim3(1), dim3(64), 0, stream, zpage);
    hipLaunchKernelGGL(k_transpose_w2, dim3(144), dim3(256), 0, stream, W2, Wt2);
    hipLaunchKernelGGL(k_conv1_lif1, dim3(512), dim3(256), 0, stream,
                       lab, W1, b1, tau1, rawp);
    hipLaunchKernelGGL(k_shift, dim3(2560), dim3(256), 0, stream, rawp, sbit);
    hipLaunchKernelGGL(k_conv2_lif2, dim3(2048), dim3(256), 0, stream,
                       sbit, Wt2, b2, tau2, zpage, s2b);
    hipLaunchKernelGGL(k_head, dim3(NT * NB * NPIX / 256), dim3(256), 0, stream,
                       s2b, Wh, bh, out);
}